// Round 5
// baseline (423.108 us; speedup 1.0000x reference)
//
#include <hip/hip_runtime.h>
#include <hip/hip_bf16.h>

#define N_BAG 500000
#define DIM   128
#define ROWS_PER_ITER 32
#define ITERS 21
#define ROWS_PER_BLOCK 672           // 32*21; 768*672 = 516096 >= 500000 (clamp tail)
#define NBLK  768                    // 256 CU x 3 blocks/CU -> one block per slot, even finish
#define GDIM  64
#define LDB   136                    // bf16 row pitch: 272B -> <=2-way LDS aliasing (free)

typedef __attribute__((ext_vector_type(8))) __bf16 bf16x8;
typedef __attribute__((ext_vector_type(4))) __bf16 bf16x4;
typedef __attribute__((ext_vector_type(4))) float  f32x4;

union BF8 { bf16x8 v; __bf16 e[8]; };

__device__ __forceinline__ float fast_rcp(float x) { return __builtin_amdgcn_rcpf(x); }

// ---------------------------------------------------------------------------
// Pass 1 (768 blocks x 256, 21 x 32-row tiles, zero grid tail).
// stg ping-pong (stgA/stgB): tile t stays in fp32 registers through [C], so
// the weighted sum runs on registers (no LDS re-read, fp32 precision) and Xs
// needs only a SINGLE buffer ([B]t's last read and [A]t+1's write are
// separated by bar2). Biases folded into MFMA C-init.
// |logit| <= ||Ww||_1 + |bw| ~= 5.1 -> exp() fp32-safe unsubtracted.
// ---------------------------------------------------------------------------
__global__ __launch_bounds__(256, 3)
void attn_pass1(const float* __restrict__ bag,
                const float* __restrict__ Wv, const float* __restrict__ bv,
                const float* __restrict__ Wu, const float* __restrict__ bu,
                const float* __restrict__ Ww, const float* __restrict__ bw,
                float* __restrict__ aOut,
                float* __restrict__ blkS, float* __restrict__ blkW,
                float* __restrict__ Eacc, float* __restrict__ Ssum)
{
    // Xs[32][LDB] bf16 (8704 B, single buffer); fin[256][4] aliases it after.
    __shared__ __align__(16) unsigned char smem[ROWS_PER_ITER * LDB * 2];
    __shared__ __align__(16) float a_part[ROWS_PER_ITER][4];   // [row][wave]

    typedef __bf16 XsT[LDB];
    XsT* Xs = (XsT*)smem;
    float (*fin)[4] = (float(*)[4])smem;

    const int tid = threadIdx.x;
    const int w   = tid >> 6;        // wave 0..3 (owns h-cols [w*32, w*32+32))
    const int L   = tid & 63;
    const int m16 = L & 15;
    const int q   = L >> 4;
    const int hh  = L >> 5;
    const int c32 = L & 31;
    const int blk = blockIdx.x;
    const int rowBase = blk * ROWS_PER_BLOCK;

    // zero the head accumulators (consumed by headA, after this kernel)
    if (blk == 0) {
        if (tid < DIM) Eacc[tid] = 0.0f;
        if (tid == DIM) Ssum[0] = 0.0f;
    }

    // ---- weight B-fragments in registers (once per block) ----
    BF8 fv[2][4], fu[2][4];
    float bvv[2], buu[2], www[2];
#pragma unroll
    for (int ht = 0; ht < 2; ++ht) {
        const int h = w*32 + ht*16 + m16;
        bvv[ht] = bv[h]; buu[ht] = bu[h]; www[ht] = Ww[h];
#pragma unroll
        for (int s = 0; s < 4; ++s) {
            const int d0 = s*32 + q*8;
            const float4 v0 = *(const float4*)(Wv + h*DIM + d0);
            const float4 v1 = *(const float4*)(Wv + h*DIM + d0 + 4);
            const float4 u0 = *(const float4*)(Wu + h*DIM + d0);
            const float4 u1 = *(const float4*)(Wu + h*DIM + d0 + 4);
            fv[ht][s].e[0]=(__bf16)v0.x; fv[ht][s].e[1]=(__bf16)v0.y;
            fv[ht][s].e[2]=(__bf16)v0.z; fv[ht][s].e[3]=(__bf16)v0.w;
            fv[ht][s].e[4]=(__bf16)v1.x; fv[ht][s].e[5]=(__bf16)v1.y;
            fv[ht][s].e[6]=(__bf16)v1.z; fv[ht][s].e[7]=(__bf16)v1.w;
            fu[ht][s].e[0]=(__bf16)u0.x; fu[ht][s].e[1]=(__bf16)u0.y;
            fu[ht][s].e[2]=(__bf16)u0.z; fu[ht][s].e[3]=(__bf16)u0.w;
            fu[ht][s].e[4]=(__bf16)u1.x; fu[ht][s].e[5]=(__bf16)u1.y;
            fu[ht][s].e[6]=(__bf16)u1.z; fu[ht][s].e[7]=(__bf16)u1.w;
        }
    }
    const float bw0 = bw[0];

    float s_acc = 0.0f;
    float wacc0 = 0.f, wacc1 = 0.f, wacc2 = 0.f, wacc3 = 0.f;
    float4 stgA[4], stgB[4];

// coalesced tile load: wave reads 2x512B rows per instr
#define LOADT(DST, T) do {                                                    \
    const int ts_ = rowBase + (T)*ROWS_PER_ITER;                              \
    _Pragma("unroll")                                                         \
    for (int i_ = 0; i_ < 4; ++i_) {                                          \
        int r_ = ts_ + i_*8 + w*2 + hh;                                       \
        if (r_ >= N_BAG) r_ = N_BAG - 1;                                      \
        DST[i_] = *(const float4*)(bag + (size_t)r_*DIM + c32*4);             \
    } } while (0)

// one 32-row tile: [A] CUR->LDS bf16 | bar1 | [B] prefetch->NXT + MFMA+psum
// | bar2 | [C] e=exp(a); wave-0 S; fp32 weighted sum from CUR registers.
#define STEP(T, CUR, NXT, DO_PF) do {                                         \
    _Pragma("unroll")                                                         \
    for (int i_ = 0; i_ < 4; ++i_) {                                          \
        const int row_ = i_*8 + w*2 + hh;                                     \
        bf16x4 pk_;                                                           \
        pk_.x = (__bf16)CUR[i_].x; pk_.y = (__bf16)CUR[i_].y;                 \
        pk_.z = (__bf16)CUR[i_].z; pk_.w = (__bf16)CUR[i_].w;                 \
        *(bf16x4*)&Xs[row_][c32*4] = pk_;                                     \
    }                                                                         \
    __syncthreads();   /* bar1: Xs visible; prev readers done */              \
    if (DO_PF) LOADT(NXT, (T) + 1);                                           \
    _Pragma("unroll")                                                         \
    for (int r_ = 0; r_ < 2; ++r_) {                                          \
        f32x4 accV_[2], accU_[2];                                             \
        _Pragma("unroll")                                                     \
        for (int ht_ = 0; ht_ < 2; ++ht_) {                                   \
            accV_[ht_] = (f32x4){bvv[ht_], bvv[ht_], bvv[ht_], bvv[ht_]};     \
            accU_[ht_] = (f32x4){buu[ht_], buu[ht_], buu[ht_], buu[ht_]};     \
        }                                                                     \
        _Pragma("unroll")                                                     \
        for (int s_ = 0; s_ < 4; ++s_) {                                      \
            const bf16x8 af_ = *(const bf16x8*)&Xs[r_*16 + m16][s_*32 + q*8]; \
            _Pragma("unroll")                                                 \
            for (int ht_ = 0; ht_ < 2; ++ht_) {                               \
                accV_[ht_] = __builtin_amdgcn_mfma_f32_16x16x32_bf16(af_, fv[ht_][s_].v, accV_[ht_], 0, 0, 0); \
                accU_[ht_] = __builtin_amdgcn_mfma_f32_16x16x32_bf16(af_, fu[ht_][s_].v, accU_[ht_], 0, 0, 0); \
            }                                                                 \
        }                                                                     \
        /* tanh(z)*sigm(y)*Ww, ONE rcp: (e^{2z}-1)e^y / ((e^{2z}+1)(e^y+1)) */\
        float psum_[4];                                                       \
        _Pragma("unroll")                                                     \
        for (int g_ = 0; g_ < 4; ++g_) {                                      \
            float p_ = 0.0f;                                                  \
            _Pragma("unroll")                                                 \
            for (int ht_ = 0; ht_ < 2; ++ht_) {                               \
                const float z_ = accV_[ht_][g_];   /* bias already in C */    \
                const float y_ = accU_[ht_][g_];                              \
                const float A_ = __expf(2.0f*z_);                             \
                const float B_ = __expf(y_);                                  \
                p_ += (A_ - 1.0f) * B_ * www[ht_] * fast_rcp((A_ + 1.0f) * (B_ + 1.0f)); \
            }                                                                 \
            p_ += __shfl_xor(p_, 1); p_ += __shfl_xor(p_, 2);                 \
            p_ += __shfl_xor(p_, 4); p_ += __shfl_xor(p_, 8);                 \
            psum_[g_] = p_;                                                   \
        }                                                                     \
        if (m16 == 0) {                                                       \
            _Pragma("unroll")                                                 \
            for (int g_ = 0; g_ < 4; ++g_)                                    \
                a_part[r_*16 + q*4 + g_][w] = psum_[g_];                      \
        }                                                                     \
    }                                                                         \
    __syncthreads();   /* bar2: a_part visible; prefetch drained */           \
    {                                                                         \
        const int li_ = L & 31;                                               \
        const float4 ap_ = *(const float4*)&a_part[li_][0];                   \
        float a_ = ap_.x + ap_.y + ap_.z + ap_.w + bw0;                       \
        const int grow_ = rowBase + (T)*ROWS_PER_ITER + li_;                  \
        if (w == 0 && L < 32 && grow_ < N_BAG) aOut[grow_] = a_;              \
        if (grow_ >= N_BAG) a_ = -1e30f;   /* e -> 0 for clamp-padded rows */ \
        const float e_ = __expf(a_);                                          \
        if (w == 0 && L < 32) s_acc += e_;   /* exactly one copy of S */      \
        _Pragma("unroll")                                                     \
        for (int i_ = 0; i_ < 4; ++i_) {                                      \
            const int row_ = i_*8 + w*2 + hh;                                 \
            const float ei_ = __shfl(e_, row_);                               \
            wacc0 += ei_ * CUR[i_].x; wacc1 += ei_ * CUR[i_].y;               \
            wacc2 += ei_ * CUR[i_].z; wacc3 += ei_ * CUR[i_].w;               \
        }                                                                     \
    } } while (0)

    LOADT(stgA, 0);
    for (int itp = 0; itp < (ITERS - 1) / 2; ++itp) {      // 10 double-steps
        STEP(2*itp,     stgA, stgB, 1);
        STEP(2*itp + 1, stgB, stgA, 1);
    }
    STEP(ITERS - 1, stgA, stgB, 0);                        // tile 20, no prefetch

#undef STEP
#undef LOADT

    // ---- block reduction: S then w[128] ----
    float st = s_acc;                 // nonzero only in wave 0 lanes 0..31
    st += __shfl_xor(st, 1);  st += __shfl_xor(st, 2);
    st += __shfl_xor(st, 4);  st += __shfl_xor(st, 8);
    st += __shfl_xor(st, 16); st += __shfl_xor(st, 32);

    __syncthreads();                 // done reading Xs; fin aliases it
    fin[tid][0] = wacc0; fin[tid][1] = wacc1;
    fin[tid][2] = wacc2; fin[tid][3] = wacc3;
    if (L == 0) a_part[0][w] = st;   // only a_part[0][0] is meaningful
    __syncthreads();
    if (tid < 128) {
        float v = 0.0f;
#pragma unroll
        for (int k = 0; k < 8; ++k) {                   // w=k>>1, hh=k&1
            const int t = (k >> 1)*64 + (k & 1)*32 + (tid >> 2);
            v += fin[t][tid & 3];
        }
        blkW[blk*DIM + tid] = v;
    }
    if (tid == 0) blkS[blk] = a_part[0][0];     // single-counted S

    (void)Eacc; (void)Ssum;
}

// ---------------------------------------------------------------------------
// headA (48 blocks x 256): E[c] += slice-sum of blkW; Ssum += slice-sum blkS.
// 48*16 = 768 = NBLK exactly.
// ---------------------------------------------------------------------------
__global__ void headA(const float* __restrict__ blkW, const float* __restrict__ blkS,
                      float* __restrict__ E, float* __restrict__ Ssum)
{
    const int tid = threadIdx.x;
    const int c = tid & 127, g = tid >> 7;
    const int b0 = blockIdx.x * 16;
    float acc = 0.0f;
#pragma unroll
    for (int t = 0; t < 8; ++t) {
        const int b = b0 + g*8 + t;
        acc += blkW[b*DIM + c];
    }
    atomicAdd(&E[c], acc);

    if (tid < 16) {
        float sv = blkS[b0 + tid];
        sv += __shfl_xor(sv, 1); sv += __shfl_xor(sv, 2);
        sv += __shfl_xor(sv, 4); sv += __shfl_xor(sv, 8);
        if (tid == 0) atomicAdd(Ssum, sv);
    }
}

// ---------------------------------------------------------------------------
// alpha_head (489 blocks x 256): every block scales its logit chunk to alpha;
// block 0 ALSO runs the head MLP f=[E/S,gfeat] -> 192->256->1 -> out[0].
// (E, Ssum complete after headA; kernel ordering guarantees visibility.)
// ---------------------------------------------------------------------------
__global__ void alpha_head(float* __restrict__ alpha, const float* __restrict__ Ssum,
                           const float* __restrict__ E, const float* __restrict__ gfeat,
                           const float* __restrict__ W1, const float* __restrict__ b1,
                           const float* __restrict__ W2, const float* __restrict__ b2,
                           float* __restrict__ out)
{
    const int tid = threadIdx.x;
    const int i = blockIdx.x * blockDim.x + tid;           // float4 index
    const float invS = 1.0f / Ssum[0];
    if (i * 4 < N_BAG) {
        float4 a4 = *(float4*)(alpha + i*4);
        a4.x = __expf(a4.x) * invS; a4.y = __expf(a4.y) * invS;
        a4.z = __expf(a4.z) * invS; a4.w = __expf(a4.w) * invS;
        *(float4*)(alpha + i*4) = a4;
    }

    if (blockIdx.x == 0) {
        __shared__ __align__(16) float f[DIM + GDIM];
        __shared__ float red[256];
        if (tid < DIM)             f[tid] = E[tid] * invS;
        else if (tid < DIM + GDIM) f[tid] = gfeat[tid - DIM];
        __syncthreads();

        float a2 = b1[tid];
        const float4* w1p = (const float4*)(W1 + tid * (DIM + GDIM));
        const float4* fp  = (const float4*)f;
#pragma unroll 4
        for (int k = 0; k < (DIM + GDIM) / 4; ++k) {
            const float4 a4 = w1p[k]; const float4 f4 = fp[k];
            a2 += a4.x*f4.x + a4.y*f4.y + a4.z*f4.z + a4.w*f4.w;
        }
        const float h = a2 > 0.0f ? a2 : 0.01f * a2;
        red[tid] = h * W2[tid]; __syncthreads();
        for (int s = 128; s > 0; s >>= 1) {
            if (tid < s) red[tid] += red[tid + s];
            __syncthreads();
        }
        if (tid == 0) out[0] = red[0] + b2[0];
    }
}

extern "C" void kernel_launch(void* const* d_in, const int* in_sizes, int n_in,
                              void* d_out, int out_size, void* d_ws, size_t ws_size,
                              hipStream_t stream)
{
    const float* bag   = (const float*)d_in[0];
    const float* gfeat = (const float*)d_in[1];
    const float* Wv    = (const float*)d_in[2];
    const float* bv    = (const float*)d_in[3];
    const float* Wu    = (const float*)d_in[4];
    const float* bu    = (const float*)d_in[5];
    const float* Ww    = (const float*)d_in[6];
    const float* bw    = (const float*)d_in[7];
    const float* W1    = (const float*)d_in[8];
    const float* b1    = (const float*)d_in[9];
    const float* W2    = (const float*)d_in[10];
    const float* b2    = (const float*)d_in[11];
    float* out = (float*)d_out;
    float* ws  = (float*)d_ws;

    float* blkS = ws;                        // 768 (pad 1024)
    float* blkW = ws + 1024;                 // 768*128 = 98304
    float* Eacc = ws + 1024 + 98304;         // 128
    float* Ssum = ws + 1024 + 98304 + 128;   // 1

    attn_pass1<<<NBLK, 256, 0, stream>>>(bag, Wv, bv, Wu, bu, Ww, bw,
                                         out + 1, blkS, blkW, Eacc, Ssum);
    headA<<<48, 256, 0, stream>>>(blkW, blkS, Eacc, Ssum);
    alpha_head<<<(N_BAG/4 + 255) / 256, 256, 0, stream>>>(out + 1, Ssum, Eacc,
                                                          gfeat, W1, b1, W2, b2, out);
}

// Round 6
// 397.157 us; speedup vs baseline: 1.0653x; 1.0653x over previous
//
#include <hip/hip_runtime.h>
#include <hip/hip_bf16.h>

#define N_BAG 500000
#define DIM   128
#define ROWS_PER_ITER 32
#define ITERS 21
#define ROWS_PER_BLOCK 672           // 32*21; 768*672 = 516096 >= 500000 (clamp tail)
#define NBLK  768                    // 256 CU x 3 blocks/CU -> one block per slot, even finish
#define GDIM  64
#define LDB   136                    // bf16 row pitch: 272B -> <=2-way LDS aliasing (free)

typedef __attribute__((ext_vector_type(8))) __bf16 bf16x8;
typedef __attribute__((ext_vector_type(4))) __bf16 bf16x4;
typedef __attribute__((ext_vector_type(4))) float  f32x4;

union BF8 { bf16x8 v; __bf16 e[8]; };

__device__ __forceinline__ float fast_rcp(float x) { return __builtin_amdgcn_rcpf(x); }

// ---------------------------------------------------------------------------
// Pass 1 (768 blocks x 256, 21 x 32-row tiles each -> zero grid tail).
// EXACT R3 inner structure (harness-proven 399.8 us): double-buffered Xs,
// stg[4] single staging set, LDS re-read in [C/D]. R5's stg ping-pong
// regressed +23 us (VGPR cliff at 3 blocks/CU) -- do not re-add live regs.
// |logit| <= ||Ww||_1 + |bw| ~= 5.1 -> exp() fp32-safe unsubtracted.
// ---------------------------------------------------------------------------
__global__ __launch_bounds__(256, 3)
void attn_pass1(const float* __restrict__ bag,
                const float* __restrict__ Wv, const float* __restrict__ bv,
                const float* __restrict__ Wu, const float* __restrict__ bu,
                const float* __restrict__ Ww, const float* __restrict__ bw,
                float* __restrict__ aOut,
                float* __restrict__ blkS, float* __restrict__ blkW,
                float* __restrict__ Eacc, float* __restrict__ Ssum)
{
    // Xs[2][32][LDB] bf16 (17408 B); fin[256][4] aliases it after the loop.
    __shared__ __align__(16) unsigned char smem[2 * ROWS_PER_ITER * LDB * 2];
    __shared__ __align__(16) float a_part[ROWS_PER_ITER][4];   // [row][wave]

    typedef __bf16 XsRow[ROWS_PER_ITER][LDB];
    XsRow* Xs = (XsRow*)smem;
    float (*fin)[4] = (float(*)[4])smem;

    const int tid = threadIdx.x;
    const int w   = tid >> 6;        // wave 0..3 (owns h-cols [w*32, w*32+32))
    const int L   = tid & 63;
    const int m16 = L & 15;
    const int q   = L >> 4;
    const int hh  = L >> 5;
    const int c32 = L & 31;
    const int blk = blockIdx.x;
    const int rowBase = blk * ROWS_PER_BLOCK;

    // zero the head accumulators (consumed by headA, after this kernel)
    if (blk == 0) {
        if (tid < DIM) Eacc[tid] = 0.0f;
        if (tid == DIM) Ssum[0] = 0.0f;
    }

    // ---- weight B-fragments in registers (once per block) ----
    BF8 fv[2][4], fu[2][4];
    float bvv[2], buu[2], www[2];
#pragma unroll
    for (int ht = 0; ht < 2; ++ht) {
        const int h = w*32 + ht*16 + m16;
        bvv[ht] = bv[h]; buu[ht] = bu[h]; www[ht] = Ww[h];
#pragma unroll
        for (int s = 0; s < 4; ++s) {
            const int d0 = s*32 + q*8;
            const float4 v0 = *(const float4*)(Wv + h*DIM + d0);
            const float4 v1 = *(const float4*)(Wv + h*DIM + d0 + 4);
            const float4 u0 = *(const float4*)(Wu + h*DIM + d0);
            const float4 u1 = *(const float4*)(Wu + h*DIM + d0 + 4);
            fv[ht][s].e[0]=(__bf16)v0.x; fv[ht][s].e[1]=(__bf16)v0.y;
            fv[ht][s].e[2]=(__bf16)v0.z; fv[ht][s].e[3]=(__bf16)v0.w;
            fv[ht][s].e[4]=(__bf16)v1.x; fv[ht][s].e[5]=(__bf16)v1.y;
            fv[ht][s].e[6]=(__bf16)v1.z; fv[ht][s].e[7]=(__bf16)v1.w;
            fu[ht][s].e[0]=(__bf16)u0.x; fu[ht][s].e[1]=(__bf16)u0.y;
            fu[ht][s].e[2]=(__bf16)u0.z; fu[ht][s].e[3]=(__bf16)u0.w;
            fu[ht][s].e[4]=(__bf16)u1.x; fu[ht][s].e[5]=(__bf16)u1.y;
            fu[ht][s].e[6]=(__bf16)u1.z; fu[ht][s].e[7]=(__bf16)u1.w;
        }
    }
    const float bw0 = bw[0];

    // ---- contiguous staging: wave reads 2x512B rows per instr, coalesced ----
    float4 stg[4];
#pragma unroll
    for (int i = 0; i < 4; ++i) {
        int r = rowBase + i*8 + w*2 + hh;
        if (r >= N_BAG) r = N_BAG - 1;
        stg[i] = *(const float4*)(bag + (size_t)r*DIM + c32*4);
    }

    float s_acc = 0.0f;
    float wacc0 = 0.f, wacc1 = 0.f, wacc2 = 0.f, wacc3 = 0.f;

    for (int it = 0; it < ITERS; ++it) {
        const int buf = it & 1;
        const int tileStart = rowBase + it*ROWS_PER_ITER;

        // --- [A] stg (fp32) -> Xs[buf] (bf16) ---
#pragma unroll
        for (int i = 0; i < 4; ++i) {
            const int row = i*8 + w*2 + hh;
            bf16x4 pk;
            pk.x = (__bf16)stg[i].x; pk.y = (__bf16)stg[i].y;
            pk.z = (__bf16)stg[i].z; pk.w = (__bf16)stg[i].w;
            *(bf16x4*)&Xs[buf][row][c32*4] = pk;
        }
        __syncthreads();   // barrier1: Xs[buf] visible

        // --- [B] prefetch next tile, then MFMA logits ---
        if (it + 1 < ITERS) {
            const int ts2 = tileStart + ROWS_PER_ITER;
#pragma unroll
            for (int i = 0; i < 4; ++i) {
                int r = ts2 + i*8 + w*2 + hh;
                if (r >= N_BAG) r = N_BAG - 1;
                stg[i] = *(const float4*)(bag + (size_t)r*DIM + c32*4);
            }
        }

#pragma unroll
        for (int r = 0; r < 2; ++r) {
            f32x4 accV[2], accU[2];
#pragma unroll
            for (int ht = 0; ht < 2; ++ht) {
                accV[ht] = (f32x4){0.f,0.f,0.f,0.f};
                accU[ht] = (f32x4){0.f,0.f,0.f,0.f};
            }
#pragma unroll
            for (int s = 0; s < 4; ++s) {
                const bf16x8 af = *(const bf16x8*)&Xs[buf][r*16 + m16][s*32 + q*8];
#pragma unroll
                for (int ht = 0; ht < 2; ++ht) {
                    accV[ht] = __builtin_amdgcn_mfma_f32_16x16x32_bf16(af, fv[ht][s].v, accV[ht], 0, 0, 0);
                    accU[ht] = __builtin_amdgcn_mfma_f32_16x16x32_bf16(af, fu[ht][s].v, accU[ht], 0, 0, 0);
                }
            }
            // tanh(z)*sigm(y)*Ww with ONE rcp: (e^{2z}-1)e^y / ((e^{2z}+1)(e^y+1))
            float psum[4];
#pragma unroll
            for (int g = 0; g < 4; ++g) {
                float p = 0.0f;
#pragma unroll
                for (int ht = 0; ht < 2; ++ht) {
                    const float z = accV[ht][g] + bvv[ht];
                    const float y = accU[ht][g] + buu[ht];
                    const float A = __expf(2.0f*z);
                    const float B = __expf(y);
                    p += (A - 1.0f) * B * www[ht] * fast_rcp((A + 1.0f) * (B + 1.0f));
                }
                p += __shfl_xor(p, 1); p += __shfl_xor(p, 2);
                p += __shfl_xor(p, 4); p += __shfl_xor(p, 8);
                psum[g] = p;
            }
            if (m16 == 0) {     // lanes 0,16,32,48 (q) write rows q*4+g, col w
#pragma unroll
                for (int g = 0; g < 4; ++g)
                    a_part[r*16 + q*4 + g][w] = psum[g];
            }
        }
        __syncthreads();   // barrier2: a_part visible; prefetch drained here

        // --- [C/D] e = exp(a); wave-0 S (single-counted); weighted sum ---
        const int li = L & 31;
        const float4 ap = *(const float4*)&a_part[li][0];
        float a = ap.x + ap.y + ap.z + ap.w + bw0;
        const int grow = tileStart + li;
        if (w == 0 && L < 32 && grow < N_BAG) aOut[grow] = a;
        if (grow >= N_BAG) a = -1e30f;            // e -> 0 for clamp-padded rows
        const float e = __expf(a);
        if (w == 0 && L < 32) s_acc += e;         // exactly one copy of S

        float s0 = 0.f, s1 = 0.f, s2 = 0.f, s3 = 0.f;
#pragma unroll
        for (int i = 0; i < 4; ++i) {
            const int row = i*8 + w*2 + hh;
            const float ei = __shfl(e, row);       // rows 0..31 live in lanes 0..31
            const bf16x4 xb = *(const bf16x4*)&Xs[buf][row][c32*4];
            s0 += ei * (float)xb.x; s1 += ei * (float)xb.y;
            s2 += ei * (float)xb.z; s3 += ei * (float)xb.w;
        }
        wacc0 += s0; wacc1 += s1; wacc2 += s2; wacc3 += s3;
        // next [A] writes Xs[buf^1]; Xs[buf] reused only after next barrier1
    }

    // ---- block reduction: S then w[128] ----
    float st = s_acc;                 // nonzero only in wave 0 lanes 0..31
    st += __shfl_xor(st, 1);  st += __shfl_xor(st, 2);
    st += __shfl_xor(st, 4);  st += __shfl_xor(st, 8);
    st += __shfl_xor(st, 16); st += __shfl_xor(st, 32);

    __syncthreads();                 // done reading Xs; fin aliases it
    fin[tid][0] = wacc0; fin[tid][1] = wacc1;
    fin[tid][2] = wacc2; fin[tid][3] = wacc3;
    if (L == 0) a_part[0][w] = st;   // only a_part[0][0] is meaningful
    __syncthreads();
    if (tid < 128) {
        float v = 0.0f;
#pragma unroll
        for (int k = 0; k < 8; ++k) {                   // w=k>>1, hh=k&1
            const int t = (k >> 1)*64 + (k & 1)*32 + (tid >> 2);
            v += fin[t][tid & 3];
        }
        blkW[blk*DIM + tid] = v;
    }
    if (tid == 0) blkS[blk] = a_part[0][0];     // single-counted S

    (void)Eacc; (void)Ssum;
}

// ---------------------------------------------------------------------------
// headA (48 blocks x 256): E[c] += slice-sum of blkW; Ssum += slice-sum blkS.
// 48*16 = 768 = NBLK exactly.
// ---------------------------------------------------------------------------
__global__ void headA(const float* __restrict__ blkW, const float* __restrict__ blkS,
                      float* __restrict__ E, float* __restrict__ Ssum)
{
    const int tid = threadIdx.x;
    const int c = tid & 127, g = tid >> 7;
    const int b0 = blockIdx.x * 16;
    float acc = 0.0f;
#pragma unroll
    for (int t = 0; t < 8; ++t) {
        const int b = b0 + g*8 + t;
        acc += blkW[b*DIM + c];
    }
    atomicAdd(&E[c], acc);

    if (tid < 16) {
        float sv = blkS[b0 + tid];
        sv += __shfl_xor(sv, 1); sv += __shfl_xor(sv, 2);
        sv += __shfl_xor(sv, 4); sv += __shfl_xor(sv, 8);
        if (tid == 0) atomicAdd(Ssum, sv);
    }
}

// ---------------------------------------------------------------------------
// alpha_head (489 blocks x 256): every block scales its logit chunk to alpha;
// block 0 ALSO runs the head MLP f=[E/S,gfeat] -> 192->256->1 -> out[0].
// (E, Ssum complete after headA; kernel ordering guarantees visibility.)
// ---------------------------------------------------------------------------
__global__ void alpha_head(float* __restrict__ alpha, const float* __restrict__ Ssum,
                           const float* __restrict__ E, const float* __restrict__ gfeat,
                           const float* __restrict__ W1, const float* __restrict__ b1,
                           const float* __restrict__ W2, const float* __restrict__ b2,
                           float* __restrict__ out)
{
    const int tid = threadIdx.x;
    const int i = blockIdx.x * blockDim.x + tid;           // float4 index
    const float invS = 1.0f / Ssum[0];
    if (i * 4 < N_BAG) {
        float4 a4 = *(float4*)(alpha + i*4);
        a4.x = __expf(a4.x) * invS; a4.y = __expf(a4.y) * invS;
        a4.z = __expf(a4.z) * invS; a4.w = __expf(a4.w) * invS;
        *(float4*)(alpha + i*4) = a4;
    }

    if (blockIdx.x == 0) {
        __shared__ __align__(16) float f[DIM + GDIM];
        __shared__ float red[256];
        if (tid < DIM)             f[tid] = E[tid] * invS;
        else if (tid < DIM + GDIM) f[tid] = gfeat[tid - DIM];
        __syncthreads();

        float a2 = b1[tid];
        const float4* w1p = (const float4*)(W1 + tid * (DIM + GDIM));
        const float4* fp  = (const float4*)f;
#pragma unroll 4
        for (int k = 0; k < (DIM + GDIM) / 4; ++k) {
            const float4 a4 = w1p[k]; const float4 f4 = fp[k];
            a2 += a4.x*f4.x + a4.y*f4.y + a4.z*f4.z + a4.w*f4.w;
        }
        const float h = a2 > 0.0f ? a2 : 0.01f * a2;
        red[tid] = h * W2[tid]; __syncthreads();
        for (int s = 128; s > 0; s >>= 1) {
            if (tid < s) red[tid] += red[tid + s];
            __syncthreads();
        }
        if (tid == 0) out[0] = red[0] + b2[0];
    }
}

extern "C" void kernel_launch(void* const* d_in, const int* in_sizes, int n_in,
                              void* d_out, int out_size, void* d_ws, size_t ws_size,
                              hipStream_t stream)
{
    const float* bag   = (const float*)d_in[0];
    const float* gfeat = (const float*)d_in[1];
    const float* Wv    = (const float*)d_in[2];
    const float* bv    = (const float*)d_in[3];
    const float* Wu    = (const float*)d_in[4];
    const float* bu    = (const float*)d_in[5];
    const float* Ww    = (const float*)d_in[6];
    const float* bw    = (const float*)d_in[7];
    const float* W1    = (const float*)d_in[8];
    const float* b1    = (const float*)d_in[9];
    const float* W2    = (const float*)d_in[10];
    const float* b2    = (const float*)d_in[11];
    float* out = (float*)d_out;
    float* ws  = (float*)d_ws;

    float* blkS = ws;                        // 768 (pad 1024)
    float* blkW = ws + 1024;                 // 768*128 = 98304
    float* Eacc = ws + 1024 + 98304;         // 128
    float* Ssum = ws + 1024 + 98304 + 128;   // 1

    attn_pass1<<<NBLK, 256, 0, stream>>>(bag, Wv, bv, Wu, bu, Ww, bw,
                                         out + 1, blkS, blkW, Eacc, Ssum);
    headA<<<48, 256, 0, stream>>>(blkW, blkS, Eacc, Ssum);
    alpha_head<<<(N_BAG/4 + 255) / 256, 256, 0, stream>>>(out + 1, Ssum, Eacc,
                                                          gfeat, W1, b1, W2, b2, out);
}